// Round 3
// baseline (53.593 us; speedup 1.0000x reference)
//
#include <hip/hip_runtime.h>

// CausalityMapBlock, B=2 C=128 H=W=7 F=49, p=1.
// Closed form (p=1): the B*C*C*F*F einsum collapses to rank-1 expressions in
// per-channel sums of the max-normalized input, S1[c] = sum_i x[c,i],
// S2[c] = sum_i x[c,i]^2:
//   num[m,n] = S2m*S2n + 2*EPS*S1m*S1n + F^2*EPS^2 + EPS
//   den[m,n] = S1m*S1n + F^2*EPS + EPS
//   ld[c]    = (S2 + 2*EPS*S1 + F*EPS^2 + EPS) / (S1 + F*EPS + EPS) + EPS
//   out[b,m,n] = (num/den + EPS) / ld[b,n]
// All nan_to_num are no-ops (x uniform [0,1), batch max > 0).
// Normalization deferred: S1 = S1raw/(M+EPS), S2 = S2raw/(M+EPS)^2.
//
// Structure: 64 blocks x 256 threads, stats redundantly computed per block
// (no inter-block dependency; 50 KB input is L2-broadcast). Thread tid owns
// channel tid: 49 contiguous floats read DIRECTLY from global (no LDS
// staging round-trip, one barrier total). Each block writes 512 coalesced
// outputs. Divides via v_rcp_f32 (rel err ~1e-6 vs 1.5e-2 threshold).

constexpr float EPS = 1e-8f;
constexpr int B = 2, C = 128, F = 49;
constexpr int BC   = B * C;        // 256
constexpr int NOUT = B * C * C;    // 32768
constexpr int BLK  = 256;
constexpr int GRID = 64;           // 512 outputs per block, 2 per thread

__global__ __launch_bounds__(BLK)
void causality_kernel(const float* __restrict__ x, float* __restrict__ out) {
    __shared__ float s1[BC], s2[BC], rld[BC];
    __shared__ float wmax[BLK / 64];

    const int tid  = threadIdx.x;
    const int lane = tid & 63;
    const int wid  = tid >> 6;

    // ---- thread tid == channel (b,c): raw sums + channel max, direct from
    // global. 196 B contiguous per thread; per-wave 12.5 KB working set is
    // L1-line-reused across the 49 iterations. ----
    const float* __restrict__ p = x + tid * F;
    float a1 = 0.f, a2 = 0.f, mx = 0.f;
#pragma unroll
    for (int k = 0; k < F; ++k) {
        float v = p[k];
        a1 += v;
        a2 += v * v;
        mx = fmaxf(mx, v);
    }

    // ---- batch max: waves 0,1 -> batch 0; waves 2,3 -> batch 1 ----
    float m = mx;
#pragma unroll
    for (int off = 32; off > 0; off >>= 1) m = fmaxf(m, __shfl_down(m, off));
    if (lane == 0) wmax[wid] = m;

    // ---- per-channel stats (normalization deferred; bmax read after bar) ----
    const float nd_c = (float)F * EPS * EPS + EPS;
    const float dd_c = (float)F * EPS + EPS;
    __syncthreads();
    const int wb = (tid >> 7) << 1;                       // 0 or 2
    const float bmax = fmaxf(wmax[wb], wmax[wb + 1]);
    const float inv = __builtin_amdgcn_rcpf(bmax + EPS);
    const float S1 = a1 * inv;
    const float S2 = a2 * inv * inv;
    s1[tid] = S1;
    s2[tid] = S2;
    const float ldv = (S2 + 2.f * EPS * S1 + nd_c) * __builtin_amdgcn_rcpf(S1 + dd_c) + EPS;
    rld[tid] = __builtin_amdgcn_rcpf(ldv);
    __syncthreads();

    // ---- 512 outputs per block, coalesced ----
    constexpr float F2 = (float)(F * F);   // 2401
    const int base = blockIdx.x * (NOUT / GRID);
#pragma unroll
    for (int j = 0; j < NOUT / GRID / BLK; ++j) {
        const int idx = base + tid + j * BLK;
        const int bb  = (idx >> 14) << 7;
        const int bm  = bb | ((idx >> 7) & (C - 1));
        const int bn  = bb | (idx & (C - 1));
        const float P   = s1[bm] * s1[bn];
        const float num = s2[bm] * s2[bn] + 2.f * EPS * P + F2 * EPS * EPS + EPS;
        const float den = P + F2 * EPS + EPS;
        const float ln  = num * __builtin_amdgcn_rcpf(den) + EPS;
        out[idx] = ln * rld[bn];
    }
}

extern "C" void kernel_launch(void* const* d_in, const int* in_sizes, int n_in,
                              void* d_out, int out_size, void* d_ws, size_t ws_size,
                              hipStream_t stream) {
    const float* x = (const float*)d_in[0];
    float* out = (float*)d_out;
    causality_kernel<<<GRID, BLK, 0, stream>>>(x, out);
}